// Round 1
// baseline (773.657 us; speedup 1.0000x reference)
//
#include <hip/hip_runtime.h>

#define WAVE 64

constexpr int D_IN = 128;
constexpr int F1 = 64;
constexpr int F2 = 128;
constexpr int NG = 64;
constexpr float NEG = 0.2f;

__device__ __forceinline__ float lrelu(float x){ return x > 0.f ? x : NEG * x; }

// ---------------- CSR build ----------------
__global__ void k_count(const int* __restrict__ dst, int E, int N, int* __restrict__ counts){
  int i = blockIdx.x * blockDim.x + threadIdx.x;
  int Et = E + N;
  int stride = gridDim.x * blockDim.x;
  for (; i < Et; i += stride){
    int d = (i < E) ? dst[i] : (i - E);
    atomicAdd(&counts[d], 1);
  }
}

// single-block scan over counts[N] -> off[N+1] (exclusive in off), cursor = exclusive
__global__ void k_scan(const int* __restrict__ counts, int N, int* __restrict__ off, int* __restrict__ cursor){
  __shared__ int lds[1024];
  __shared__ int carry_s;
  if (threadIdx.x == 0) carry_s = 0;
  __syncthreads();
  for (int base = 0; base < N; base += 1024){
    int i = base + (int)threadIdx.x;
    int v = (i < N) ? counts[i] : 0;
    lds[threadIdx.x] = v;
    __syncthreads();
    for (int s = 1; s < 1024; s <<= 1){
      int t = (threadIdx.x >= (unsigned)s) ? lds[threadIdx.x - s] : 0;
      __syncthreads();
      lds[threadIdx.x] += t;
      __syncthreads();
    }
    int inc = lds[threadIdx.x] + carry_s;
    if (i < N){ off[i + 1] = inc; cursor[i] = inc - v; }
    __syncthreads();
    if (threadIdx.x == 1023) carry_s = inc;
    __syncthreads();
  }
  if (threadIdx.x == 0) off[0] = 0;
}

__global__ void k_fill(const int* __restrict__ src, const int* __restrict__ dst, int E, int N,
                       int* __restrict__ cursor, int* __restrict__ csr_src){
  int i = blockIdx.x * blockDim.x + threadIdx.x;
  int Et = E + N;
  int stride = gridDim.x * blockDim.x;
  for (; i < Et; i += stride){
    int s, d;
    if (i < E){ s = src[i]; d = dst[i]; } else { s = i - E; d = s; }
    int pos = atomicAdd(&cursor[d], 1);
    csr_src[pos] = s;
  }
}

// ---------------- GEMM: C[N,FO] = A[N,FI] @ W[FI,FO]; plus as/ad dots ----------------
template<int FI, int FO>
__global__ void k_gemm(const float* __restrict__ A, const float* __restrict__ W,
                       const float* __restrict__ avs, const float* __restrict__ avd,
                       float* __restrict__ C, float* __restrict__ as_, float* __restrict__ ad_,
                       int N){
  constexpr int CPL = FO / WAVE;         // cols per lane
  int lane = threadIdx.x % WAVE;
  int wave = (blockIdx.x * blockDim.x + threadIdx.x) / WAVE;
  int r0 = wave * 4;
  if (r0 >= N) return;
  float acc[4][CPL];
  #pragma unroll
  for (int r = 0; r < 4; ++r)
    #pragma unroll
    for (int c = 0; c < CPL; ++c) acc[r][c] = 0.f;

  for (int k = 0; k < FI; ++k){
    float w[CPL];
    #pragma unroll
    for (int c = 0; c < CPL; ++c) w[c] = W[k * FO + lane + c * WAVE];
    #pragma unroll
    for (int r = 0; r < 4; ++r){
      float a = A[(size_t)(r0 + r) * FI + k];
      #pragma unroll
      for (int c = 0; c < CPL; ++c) acc[r][c] += a * w[c];
    }
  }
  #pragma unroll
  for (int r = 0; r < 4; ++r){
    float ss = 0.f, sd = 0.f;
    #pragma unroll
    for (int c = 0; c < CPL; ++c){
      float h = acc[r][c];
      C[(size_t)(r0 + r) * FO + lane + c * WAVE] = h;
      ss += h * avs[lane + c * WAVE];
      sd += h * avd[lane + c * WAVE];
    }
    #pragma unroll
    for (int o = 32; o; o >>= 1){
      ss += __shfl_xor(ss, o);
      sd += __shfl_xor(sd, o);
    }
    if (lane == 0){ as_[r0 + r] = ss; ad_[r0 + r] = sd; }
  }
}

// ---------------- per-node softmax + weighted aggregation (one wave per node) ----------------
template<int F>
__global__ void k_node(const int* __restrict__ off, const int* __restrict__ csr_src,
                       const float* __restrict__ h, const float* __restrict__ as_,
                       const float* __restrict__ ad_, const float* __restrict__ bias,
                       float* __restrict__ outp, int N){
  int lane = threadIdx.x % WAVE;
  int node = (blockIdx.x * blockDim.x + threadIdx.x) / WAVE;
  if (node >= N) return;
  int o0 = off[node], o1 = off[node + 1];
  float add = ad_[node];

  // phase 1: max over incoming edges
  float lmax = -1e30f;
  for (int j = o0 + lane; j < o1; j += WAVE){
    float e = lrelu(as_[csr_src[j]] + add);
    lmax = fmaxf(lmax, e);
  }
  #pragma unroll
  for (int s = 32; s; s >>= 1) lmax = fmaxf(lmax, __shfl_xor(lmax, s));
  float m = lmax;

  // phase 2: denom
  float lsum = 0.f;
  for (int j = o0 + lane; j < o1; j += WAVE){
    float e = lrelu(as_[csr_src[j]] + add);
    lsum += __expf(e - m);
  }
  #pragma unroll
  for (int s = 32; s; s >>= 1) lsum += __shfl_xor(lsum, s);
  float inv = 1.f / (lsum + 1e-16f);

  // phase 3: weighted sum of h[src]
  constexpr int CPL = F / WAVE;
  float acc[CPL];
  #pragma unroll
  for (int c = 0; c < CPL; ++c) acc[c] = 0.f;
  for (int j = o0; j < o1; ++j){
    int s = csr_src[j];
    float e = lrelu(as_[s] + add);
    float alpha = __expf(e - m) * inv;
    #pragma unroll
    for (int c = 0; c < CPL; ++c) acc[c] += alpha * h[(size_t)s * F + lane + c * WAVE];
  }
  #pragma unroll
  for (int c = 0; c < CPL; ++c){
    float v = acc[c] + bias[lane + c * WAVE];
    outp[(size_t)node * F + lane + c * WAVE] = fmaxf(v, 0.f);
  }
}

// ---------------- pooling (batch sorted): strip reduction ----------------
__global__ void k_pool(const float* __restrict__ h, const int* __restrict__ batch,
                       float* __restrict__ pool, int* __restrict__ cnt, int N, int strip){
  int f = threadIdx.x;  // 0..127
  int n0 = blockIdx.x * strip;
  if (n0 >= N) return;
  int n1 = min(n0 + strip, N);
  int g = batch[n0];
  float acc = 0.f;
  int c = 0;
  for (int n = n0; n < n1; ++n){
    int gn = batch[n];
    if (gn != g){
      atomicAdd(&pool[g * F2 + f], acc);
      if (f == 0) atomicAdd(&cnt[g], c);
      acc = 0.f; c = 0; g = gn;
    }
    acc += h[(size_t)n * F2 + f];
    c++;
  }
  atomicAdd(&pool[g * F2 + f], acc);
  if (f == 0) atomicAdd(&cnt[g], c);
}

// ---------------- final FC: out[g][o] = (pool[g]/cnt[g]) . Wfc[:,o] + bfc[o] ----------------
__global__ void k_fc(const float* __restrict__ pool, const int* __restrict__ cnt,
                     const float* __restrict__ Wfc, const float* __restrict__ bfc,
                     float* __restrict__ out){
  int g = blockIdx.x, o = threadIdx.x;  // 64 x 64
  __shared__ float p[F2];
  float invc = 1.f / fmaxf((float)cnt[g], 1.f);
  for (int k = threadIdx.x; k < F2; k += 64) p[k] = pool[g * F2 + k] * invc;
  __syncthreads();
  float acc = bfc[o];
  for (int k = 0; k < F2; ++k) acc += p[k] * Wfc[k * 64 + o];
  out[g * 64 + o] = acc;
}

extern "C" void kernel_launch(void* const* d_in, const int* in_sizes, int n_in,
                              void* d_out, int out_size, void* d_ws, size_t ws_size,
                              hipStream_t stream){
  const float* x    = (const float*)d_in[0];
  const int*   edge = (const int*)d_in[1];
  const int*   batch= (const int*)d_in[2];
  const float* W1   = (const float*)d_in[3];
  const float* av_s1= (const float*)d_in[4];
  const float* av_d1= (const float*)d_in[5];
  const float* b1   = (const float*)d_in[6];
  const float* W2   = (const float*)d_in[7];
  const float* av_s2= (const float*)d_in[8];
  const float* av_d2= (const float*)d_in[9];
  const float* b2   = (const float*)d_in[10];
  const float* Wfc  = (const float*)d_in[11];
  const float* bfc  = (const float*)d_in[12];
  float* out = (float*)d_out;

  const int N  = in_sizes[2];
  const int E  = in_sizes[1] / 2;
  const int Et = E + N;
  const int* src = edge;
  const int* dst = edge + E;

  char* p = (char*)d_ws;
  auto alloc = [&](size_t bytes)->void*{
    void* r = (void*)p;
    p += (bytes + 255) & ~(size_t)255;
    return r;
  };
  float* h1   = (float*)alloc((size_t)N * F1 * 4);
  float* h1r  = (float*)alloc((size_t)N * F1 * 4);
  float* h2   = (float*)alloc((size_t)N * F2 * 4);
  float* h2r  = (float*)alloc((size_t)N * F2 * 4);
  float* as1  = (float*)alloc((size_t)N * 4);
  float* ad1  = (float*)alloc((size_t)N * 4);
  float* as2  = (float*)alloc((size_t)N * 4);
  float* ad2  = (float*)alloc((size_t)N * 4);
  float* pool = (float*)alloc((size_t)NG * F2 * 4);
  int* counts = (int*)alloc((size_t)N * 4);
  int* off    = (int*)alloc((size_t)(N + 1) * 4);
  int* cursor = (int*)alloc((size_t)N * 4);
  int* csr_src= (int*)alloc((size_t)Et * 4);
  int* cnt    = (int*)alloc((size_t)NG * 4);

  hipMemsetAsync(counts, 0, (size_t)N * 4, stream);
  hipMemsetAsync(pool, 0, (size_t)NG * F2 * 4, stream);
  hipMemsetAsync(cnt, 0, (size_t)NG * 4, stream);

  // CSR build
  int eb = 2048;
  k_count<<<eb, 256, 0, stream>>>(dst, E, N, counts);
  k_scan<<<1, 1024, 0, stream>>>(counts, N, off, cursor);
  k_fill<<<eb, 256, 0, stream>>>(src, dst, E, N, cursor, csr_src);

  // layer 1
  int gemm_waves = (N + 3) / 4;
  int gemm_blocks = (gemm_waves + 3) / 4;
  k_gemm<D_IN, F1><<<gemm_blocks, 256, 0, stream>>>(x, W1, av_s1, av_d1, h1, as1, ad1, N);
  int node_blocks = (N + 3) / 4;  // 4 waves per 256-thread block
  k_node<F1><<<node_blocks, 256, 0, stream>>>(off, csr_src, h1, as1, ad1, b1, h1r, N);

  // layer 2
  k_gemm<F1, F2><<<gemm_blocks, 256, 0, stream>>>(h1r, W2, av_s2, av_d2, h2, as2, ad2, N);
  k_node<F2><<<node_blocks, 256, 0, stream>>>(off, csr_src, h2, as2, ad2, b2, h2r, N);

  // pooling + FC
  int strip = 128;
  int pool_blocks = (N + strip - 1) / strip;
  k_pool<<<pool_blocks, F2, 0, stream>>>(h2r, batch, pool, cnt, N, strip);
  k_fc<<<NG, 64, 0, stream>>>(pool, cnt, Wfc, bfc, out);
}

// Round 2
// 544.594 us; speedup vs baseline: 1.4206x; 1.4206x over previous
//
#include <hip/hip_runtime.h>

#define WAVE 64

constexpr int D_IN = 128;
constexpr int F1 = 64;
constexpr int F2 = 128;
constexpr int NG = 64;
constexpr float NEG = 0.2f;

__device__ __forceinline__ float lrelu(float x){ return x > 0.f ? x : NEG * x; }

// ---------------- CSR build ----------------
__global__ void k_count(const int* __restrict__ dst, int E, int N, int* __restrict__ counts){
  int i = blockIdx.x * blockDim.x + threadIdx.x;
  int Et = E + N;
  int stride = gridDim.x * blockDim.x;
  for (; i < Et; i += stride){
    int d = (i < E) ? dst[i] : (i - E);
    atomicAdd(&counts[d], 1);
  }
}

// hierarchical scan: per-block sums -> scan of block sums -> per-block scan
constexpr int SCAN_BLOCKS = 64;

__global__ void k_bsum(const int* __restrict__ counts, int N, int chunk, int* __restrict__ bsum){
  int b = blockIdx.x;
  int s0 = b * chunk, s1 = min(s0 + chunk, N);
  int v = 0;
  for (int i = s0 + (int)threadIdx.x; i < s1; i += (int)blockDim.x) v += counts[i];
  __shared__ int red[4];
  #pragma unroll
  for (int o = 32; o; o >>= 1) v += __shfl_xor(v, o);
  if ((threadIdx.x & 63) == 0) red[threadIdx.x >> 6] = v;
  __syncthreads();
  if (threadIdx.x == 0) bsum[b] = red[0] + red[1] + red[2] + red[3];
}

__global__ void k_bscan(int* __restrict__ bsum, int nb){
  int lane = threadIdx.x;
  int v = (lane < nb) ? bsum[lane] : 0;
  int inc = v;
  #pragma unroll
  for (int s = 1; s < 64; s <<= 1){
    int t = __shfl_up(inc, s);
    if (lane >= s) inc += t;
  }
  if (lane < nb) bsum[lane] = inc - v;  // exclusive prefix
}

__global__ void k_scan_fin(const int* __restrict__ counts, int N, int chunk,
                           const int* __restrict__ bpre, int* __restrict__ off,
                           int* __restrict__ cursor){
  int b = blockIdx.x;
  int s0 = b * chunk, s1 = min(s0 + chunk, N);
  __shared__ int lds[256];
  int carry = bpre[b];
  for (int base = s0; base < s1; base += 256){
    int i = base + (int)threadIdx.x;
    int v = (i < s1) ? counts[i] : 0;
    lds[threadIdx.x] = v;
    __syncthreads();
    #pragma unroll
    for (int s = 1; s < 256; s <<= 1){
      int t = (threadIdx.x >= (unsigned)s) ? lds[threadIdx.x - s] : 0;
      __syncthreads();
      lds[threadIdx.x] += t;
      __syncthreads();
    }
    int inc = lds[threadIdx.x] + carry;
    if (i < s1){ off[i + 1] = inc; cursor[i] = inc - v; }
    int total = lds[255];
    carry += total;
    __syncthreads();
  }
  if (b == 0 && threadIdx.x == 0) off[0] = 0;
}

__global__ void k_fill(const int* __restrict__ src, const int* __restrict__ dst, int E, int N,
                       int* __restrict__ cursor, int* __restrict__ csr_src){
  int i = blockIdx.x * blockDim.x + threadIdx.x;
  int Et = E + N;
  int stride = gridDim.x * blockDim.x;
  for (; i < Et; i += stride){
    int s, d;
    if (i < E){ s = src[i]; d = dst[i]; } else { s = i - E; d = s; }
    int pos = atomicAdd(&cursor[d], 1);
    csr_src[pos] = s;
  }
}

// ---------------- GEMM: C[N,FO] = A[N,FI] @ W[FI,FO]; plus as/ad dots ----------------
template<int FI, int FO>
__global__ void k_gemm(const float* __restrict__ A, const float* __restrict__ W,
                       const float* __restrict__ avs, const float* __restrict__ avd,
                       float* __restrict__ C, float* __restrict__ as_, float* __restrict__ ad_,
                       int N){
  constexpr int CPL = FO / WAVE;         // cols per lane
  int lane = threadIdx.x & (WAVE - 1);
  int wave = (blockIdx.x * blockDim.x + threadIdx.x) / WAVE;
  int r0 = wave * 4;
  if (r0 >= N) return;
  int rmax = min(4, N - r0);
  float acc[4][CPL];
  #pragma unroll
  for (int r = 0; r < 4; ++r)
    #pragma unroll
    for (int c = 0; c < CPL; ++c) acc[r][c] = 0.f;

  for (int k = 0; k < FI; k += 4){
    float w[4][CPL];
    #pragma unroll
    for (int kk = 0; kk < 4; ++kk)
      #pragma unroll
      for (int c = 0; c < CPL; ++c) w[kk][c] = W[(k + kk) * FO + lane + c * WAVE];
    #pragma unroll
    for (int r = 0; r < 4; ++r){
      if (r < rmax){
        float4 a = *(const float4*)&A[(size_t)(r0 + r) * FI + k];
        #pragma unroll
        for (int c = 0; c < CPL; ++c)
          acc[r][c] += a.x * w[0][c] + a.y * w[1][c] + a.z * w[2][c] + a.w * w[3][c];
      }
    }
  }
  #pragma unroll
  for (int r = 0; r < 4; ++r){
    if (r < rmax){
      float ss = 0.f, sd = 0.f;
      #pragma unroll
      for (int c = 0; c < CPL; ++c){
        float h = acc[r][c];
        C[(size_t)(r0 + r) * FO + lane + c * WAVE] = h;
        ss += h * avs[lane + c * WAVE];
        sd += h * avd[lane + c * WAVE];
      }
      #pragma unroll
      for (int o = 32; o; o >>= 1){
        ss += __shfl_xor(ss, o);
        sd += __shfl_xor(sd, o);
      }
      if (lane == 0){ as_[r0 + r] = ss; ad_[r0 + r] = sd; }
    }
  }
}

// ---------------- fused softmax + aggregation, single pass, unroll x4 ----------------
// No max subtraction: out = sum_j exp(e_j) h_j / sum_j exp(e_j); e bounded ~ +-12 so safe in fp32.
template<int F>
__global__ void k_node(const int* __restrict__ off, const int* __restrict__ csr_src,
                       const float* __restrict__ h, const float* __restrict__ as_,
                       const float* __restrict__ ad_, const float* __restrict__ bias,
                       float* __restrict__ outp, int N){
  constexpr int CPL = F / WAVE;
  int lane = threadIdx.x & (WAVE - 1);
  int node = (blockIdx.x * blockDim.x + threadIdx.x) >> 6;
  if (node >= N) return;
  int o0 = off[node], o1 = off[node + 1];
  float add = ad_[node];
  float acc[CPL];
  #pragma unroll
  for (int c = 0; c < CPL; ++c) acc[c] = 0.f;
  float wsum = 0.f;
  int j = o0;
  for (; j + 4 <= o1; j += 4){
    int s0 = csr_src[j], s1 = csr_src[j + 1], s2 = csr_src[j + 2], s3 = csr_src[j + 3];
    float r0[CPL], r1[CPL], r2[CPL], r3[CPL];
    #pragma unroll
    for (int c = 0; c < CPL; ++c){
      r0[c] = h[(size_t)s0 * F + lane + c * WAVE];
      r1[c] = h[(size_t)s1 * F + lane + c * WAVE];
      r2[c] = h[(size_t)s2 * F + lane + c * WAVE];
      r3[c] = h[(size_t)s3 * F + lane + c * WAVE];
    }
    float w0 = __expf(lrelu(as_[s0] + add));
    float w1 = __expf(lrelu(as_[s1] + add));
    float w2 = __expf(lrelu(as_[s2] + add));
    float w3 = __expf(lrelu(as_[s3] + add));
    wsum += (w0 + w1) + (w2 + w3);
    #pragma unroll
    for (int c = 0; c < CPL; ++c)
      acc[c] += w0 * r0[c] + w1 * r1[c] + w2 * r2[c] + w3 * r3[c];
  }
  for (; j < o1; ++j){
    int s = csr_src[j];
    float w = __expf(lrelu(as_[s] + add));
    wsum += w;
    #pragma unroll
    for (int c = 0; c < CPL; ++c) acc[c] += w * h[(size_t)s * F + lane + c * WAVE];
  }
  float inv = 1.f / (wsum + 1e-16f);
  #pragma unroll
  for (int c = 0; c < CPL; ++c){
    float v = acc[c] * inv + bias[lane + c * WAVE];
    outp[(size_t)node * F + lane + c * WAVE] = fmaxf(v, 0.f);
  }
}

// ---------------- pooling (batch sorted): strip reduction ----------------
__global__ void k_pool(const float* __restrict__ h, const int* __restrict__ batch,
                       float* __restrict__ pool, int* __restrict__ cnt, int N, int strip){
  int f = threadIdx.x;  // 0..127
  int n0 = blockIdx.x * strip;
  if (n0 >= N) return;
  int n1 = min(n0 + strip, N);
  int g = batch[n0];
  float acc = 0.f;
  int c = 0;
  for (int n = n0; n < n1; ++n){
    int gn = batch[n];
    if (gn != g){
      atomicAdd(&pool[g * F2 + f], acc);
      if (f == 0) atomicAdd(&cnt[g], c);
      acc = 0.f; c = 0; g = gn;
    }
    acc += h[(size_t)n * F2 + f];
    c++;
  }
  atomicAdd(&pool[g * F2 + f], acc);
  if (f == 0) atomicAdd(&cnt[g], c);
}

// ---------------- final FC ----------------
__global__ void k_fc(const float* __restrict__ pool, const int* __restrict__ cnt,
                     const float* __restrict__ Wfc, const float* __restrict__ bfc,
                     float* __restrict__ out){
  int g = blockIdx.x, o = threadIdx.x;  // 64 x 64
  __shared__ float p[F2];
  float invc = 1.f / fmaxf((float)cnt[g], 1.f);
  for (int k = threadIdx.x; k < F2; k += 64) p[k] = pool[g * F2 + k] * invc;
  __syncthreads();
  float acc = bfc[o];
  for (int k = 0; k < F2; ++k) acc += p[k] * Wfc[k * 64 + o];
  out[g * 64 + o] = acc;
}

extern "C" void kernel_launch(void* const* d_in, const int* in_sizes, int n_in,
                              void* d_out, int out_size, void* d_ws, size_t ws_size,
                              hipStream_t stream){
  const float* x    = (const float*)d_in[0];
  const int*   edge = (const int*)d_in[1];
  const int*   batch= (const int*)d_in[2];
  const float* W1   = (const float*)d_in[3];
  const float* av_s1= (const float*)d_in[4];
  const float* av_d1= (const float*)d_in[5];
  const float* b1   = (const float*)d_in[6];
  const float* W2   = (const float*)d_in[7];
  const float* av_s2= (const float*)d_in[8];
  const float* av_d2= (const float*)d_in[9];
  const float* b2   = (const float*)d_in[10];
  const float* Wfc  = (const float*)d_in[11];
  const float* bfc  = (const float*)d_in[12];
  float* out = (float*)d_out;

  const int N  = in_sizes[2];
  const int E  = in_sizes[1] / 2;
  const int Et = E + N;
  const int* src = edge;
  const int* dst = edge + E;

  char* p = (char*)d_ws;
  auto alloc = [&](size_t bytes)->void*{
    void* r = (void*)p;
    p += (bytes + 255) & ~(size_t)255;
    return r;
  };
  float* h1   = (float*)alloc((size_t)N * F1 * 4);
  float* h1r  = (float*)alloc((size_t)N * F1 * 4);
  float* h2   = (float*)alloc((size_t)N * F2 * 4);
  float* h2r  = (float*)alloc((size_t)N * F2 * 4);
  float* as1  = (float*)alloc((size_t)N * 4);
  float* ad1  = (float*)alloc((size_t)N * 4);
  float* as2  = (float*)alloc((size_t)N * 4);
  float* ad2  = (float*)alloc((size_t)N * 4);
  float* pool = (float*)alloc((size_t)NG * F2 * 4);
  int* counts = (int*)alloc((size_t)N * 4);
  int* off    = (int*)alloc((size_t)(N + 1) * 4);
  int* cursor = (int*)alloc((size_t)N * 4);
  int* csr_src= (int*)alloc((size_t)Et * 4);
  int* bsum   = (int*)alloc((size_t)SCAN_BLOCKS * 4);
  int* cnt    = (int*)alloc((size_t)NG * 4);

  hipMemsetAsync(counts, 0, (size_t)N * 4, stream);
  hipMemsetAsync(pool, 0, (size_t)NG * F2 * 4, stream);
  hipMemsetAsync(cnt, 0, (size_t)NG * 4, stream);

  // CSR build
  int eb = 2048;
  int chunk = (N + SCAN_BLOCKS - 1) / SCAN_BLOCKS;
  k_count<<<eb, 256, 0, stream>>>(dst, E, N, counts);
  k_bsum<<<SCAN_BLOCKS, 256, 0, stream>>>(counts, N, chunk, bsum);
  k_bscan<<<1, 64, 0, stream>>>(bsum, SCAN_BLOCKS);
  k_scan_fin<<<SCAN_BLOCKS, 256, 0, stream>>>(counts, N, chunk, bsum, off, cursor);
  k_fill<<<eb, 256, 0, stream>>>(src, dst, E, N, cursor, csr_src);

  // layer 1
  int gemm_waves = (N + 3) / 4;
  int gemm_blocks = (gemm_waves + 3) / 4;
  k_gemm<D_IN, F1><<<gemm_blocks, 256, 0, stream>>>(x, W1, av_s1, av_d1, h1, as1, ad1, N);
  int node_blocks = (N + 3) / 4;  // 4 waves per 256-thread block
  k_node<F1><<<node_blocks, 256, 0, stream>>>(off, csr_src, h1, as1, ad1, b1, h1r, N);

  // layer 2
  k_gemm<F1, F2><<<gemm_blocks, 256, 0, stream>>>(h1r, W2, av_s2, av_d2, h2, as2, ad2, N);
  k_node<F2><<<node_blocks, 256, 0, stream>>>(off, csr_src, h2, as2, ad2, b2, h2r, N);

  // pooling + FC
  int strip = 128;
  int pool_blocks = (N + strip - 1) / strip;
  k_pool<<<pool_blocks, F2, 0, stream>>>(h2r, batch, pool, cnt, N, strip);
  k_fc<<<NG, 64, 0, stream>>>(pool, cnt, Wfc, bfc, out);
}

// Round 3
// 386.220 us; speedup vs baseline: 2.0032x; 1.4101x over previous
//
#include <hip/hip_runtime.h>

#define WAVE 64

constexpr int D_IN = 128;
constexpr int F1 = 64;
constexpr int F2 = 128;
constexpr int NG = 64;
constexpr float NEG = 0.2f;
constexpr int NBLK1 = 512;       // level-1 binning blocks

__device__ __forceinline__ float lrelu(float x){ return x > 0.f ? x : NEG * x; }

// ================= CSR build: two-level LDS-binned counting sort =================
// bucket = dst >> 8  (NB = ceil(N/256) buckets, NB <= 256 required -> N <= 65536)
// entry  = (src << 8) | (dst & 255)

// L1 pass 1: per-block histogram over coarse buckets
__global__ void k_hist(const int* __restrict__ src, const int* __restrict__ dst,
                       int E, int N, int NB, int chunk, int* __restrict__ cnt1){
  __shared__ int hist[256];
  int b = blockIdx.x;
  for (int t = threadIdx.x; t < NB; t += blockDim.x) hist[t] = 0;
  __syncthreads();
  int Et = E + N;
  int s0 = b * chunk, s1 = min(s0 + chunk, Et);
  for (int i = s0 + (int)threadIdx.x; i < s1; i += (int)blockDim.x){
    int d = (i < E) ? dst[i] : (i - E);
    atomicAdd(&hist[d >> 8], 1);
  }
  __syncthreads();
  for (int t = threadIdx.x; t < NB; t += blockDim.x) cnt1[t * NBLK1 + b] = hist[t];
}

// scan each bucket's 512 per-block counts -> exclusive prefixes (in place) + bucket totals
__global__ void k_colscan(int* __restrict__ cnt1, int* __restrict__ btot){
  __shared__ int lds[256];
  int b = blockIdx.x;
  int t = threadIdx.x;
  int v0 = cnt1[b * NBLK1 + 2 * t], v1 = cnt1[b * NBLK1 + 2 * t + 1];
  int p = v0 + v1;
  lds[t] = p; __syncthreads();
  #pragma unroll
  for (int s = 1; s < 256; s <<= 1){
    int u = (t >= s) ? lds[t - s] : 0;
    __syncthreads(); lds[t] += u; __syncthreads();
  }
  int epre = lds[t] - p;
  cnt1[b * NBLK1 + 2 * t] = epre;
  cnt1[b * NBLK1 + 2 * t + 1] = epre + v0;
  if (t == 255) btot[b] = lds[255];
}

// exclusive scan of bucket totals -> bucket bases; also off[N] = Et
__global__ void k_bucketscan(const int* __restrict__ btot, int NB, int Et,
                             int* __restrict__ bbase, int* __restrict__ off, int N){
  __shared__ int lds[256];
  int t = threadIdx.x;
  int v = (t < NB) ? btot[t] : 0;
  lds[t] = v; __syncthreads();
  #pragma unroll
  for (int s = 1; s < 256; s <<= 1){
    int u = (t >= s) ? lds[t - s] : 0;
    __syncthreads(); lds[t] += u; __syncthreads();
  }
  if (t < NB) bbase[t] = lds[t] - v;
  if (t == 0){ bbase[NB] = Et; off[N] = Et; }
}

// L1 pass 2: append entries to this block's own segment of each bucket (coalesced-per-line)
__global__ void k_scatter1(const int* __restrict__ src, const int* __restrict__ dst,
                           int E, int N, int NB, int chunk,
                           const int* __restrict__ cnt1, const int* __restrict__ bbase,
                           int* __restrict__ tmp){
  __shared__ int cur[256];
  int b = blockIdx.x;
  for (int t = threadIdx.x; t < NB; t += blockDim.x) cur[t] = bbase[t] + cnt1[t * NBLK1 + b];
  __syncthreads();
  int Et = E + N;
  int s0 = b * chunk, s1 = min(s0 + chunk, Et);
  for (int i = s0 + (int)threadIdx.x; i < s1; i += (int)blockDim.x){
    int s, d;
    if (i < E){ s = src[i]; d = dst[i]; } else { s = d = i - E; }
    int bk = d >> 8;
    int p = atomicAdd(&cur[bk], 1);
    tmp[p] = (s << 8) | (d & 255);
  }
}

// L2: per-bucket counting sort by low 8 dst bits -> final csr_src + off[]
__global__ void k_sort2(const int* __restrict__ tmp, const int* __restrict__ bbase,
                        int N, int* __restrict__ off, int* __restrict__ csr_src){
  __shared__ int hist[256];
  __shared__ int pre[256];
  int b = blockIdx.x;
  int t = threadIdx.x;
  hist[t] = 0;
  __syncthreads();
  int g0 = bbase[b], g1 = bbase[b + 1];
  for (int i = g0 + t; i < g1; i += 256) atomicAdd(&hist[tmp[i] & 255], 1);
  __syncthreads();
  int v = hist[t];
  pre[t] = v; __syncthreads();
  #pragma unroll
  for (int s = 1; s < 256; s <<= 1){
    int u = (t >= s) ? pre[t - s] : 0;
    __syncthreads(); pre[t] += u; __syncthreads();
  }
  int ex = pre[t] - v;
  int node = (b << 8) + t;
  if (node < N) off[node] = g0 + ex;
  hist[t] = ex;         // reuse as cursor
  __syncthreads();
  for (int i = g0 + t; i < g1; i += 256){
    int e = tmp[i];
    int p = g0 + atomicAdd(&hist[e & 255], 1);
    csr_src[p] = e >> 8;
  }
}

// ---------------- GEMM: C[N,FO] = A[N,FI] @ W[FI,FO]; plus as/ad dots ----------------
template<int FI, int FO>
__global__ void k_gemm(const float* __restrict__ A, const float* __restrict__ W,
                       const float* __restrict__ avs, const float* __restrict__ avd,
                       float* __restrict__ C, float* __restrict__ as_, float* __restrict__ ad_,
                       int N){
  constexpr int CPL = FO / WAVE;         // cols per lane
  int lane = threadIdx.x & (WAVE - 1);
  int wave = (blockIdx.x * blockDim.x + threadIdx.x) / WAVE;
  int r0 = wave * 4;
  if (r0 >= N) return;
  int rmax = min(4, N - r0);
  float acc[4][CPL];
  #pragma unroll
  for (int r = 0; r < 4; ++r)
    #pragma unroll
    for (int c = 0; c < CPL; ++c) acc[r][c] = 0.f;

  for (int k = 0; k < FI; k += 4){
    float w[4][CPL];
    #pragma unroll
    for (int kk = 0; kk < 4; ++kk)
      #pragma unroll
      for (int c = 0; c < CPL; ++c) w[kk][c] = W[(k + kk) * FO + lane + c * WAVE];
    #pragma unroll
    for (int r = 0; r < 4; ++r){
      if (r < rmax){
        float4 a = *(const float4*)&A[(size_t)(r0 + r) * FI + k];
        #pragma unroll
        for (int c = 0; c < CPL; ++c)
          acc[r][c] += a.x * w[0][c] + a.y * w[1][c] + a.z * w[2][c] + a.w * w[3][c];
      }
    }
  }
  #pragma unroll
  for (int r = 0; r < 4; ++r){
    if (r < rmax){
      float ss = 0.f, sd = 0.f;
      #pragma unroll
      for (int c = 0; c < CPL; ++c){
        float h = acc[r][c];
        C[(size_t)(r0 + r) * FO + lane + c * WAVE] = h;
        ss += h * avs[lane + c * WAVE];
        sd += h * avd[lane + c * WAVE];
      }
      #pragma unroll
      for (int o = 32; o; o >>= 1){
        ss += __shfl_xor(ss, o);
        sd += __shfl_xor(sd, o);
      }
      if (lane == 0){ as_[r0 + r] = ss; ad_[r0 + r] = sd; }
    }
  }
}

// ---------------- fused softmax + aggregation, single pass, unroll x4 ----------------
template<int F>
__global__ void k_node(const int* __restrict__ off, const int* __restrict__ csr_src,
                       const float* __restrict__ h, const float* __restrict__ as_,
                       const float* __restrict__ ad_, const float* __restrict__ bias,
                       float* __restrict__ outp, int N){
  constexpr int CPL = F / WAVE;
  int lane = threadIdx.x & (WAVE - 1);
  int node = (blockIdx.x * blockDim.x + threadIdx.x) >> 6;
  if (node >= N) return;
  int o0 = off[node], o1 = off[node + 1];
  float add = ad_[node];
  float acc[CPL];
  #pragma unroll
  for (int c = 0; c < CPL; ++c) acc[c] = 0.f;
  float wsum = 0.f;
  int j = o0;
  for (; j + 4 <= o1; j += 4){
    int s0 = csr_src[j], s1 = csr_src[j + 1], s2 = csr_src[j + 2], s3 = csr_src[j + 3];
    float r0[CPL], r1[CPL], r2[CPL], r3[CPL];
    #pragma unroll
    for (int c = 0; c < CPL; ++c){
      r0[c] = h[(size_t)s0 * F + lane + c * WAVE];
      r1[c] = h[(size_t)s1 * F + lane + c * WAVE];
      r2[c] = h[(size_t)s2 * F + lane + c * WAVE];
      r3[c] = h[(size_t)s3 * F + lane + c * WAVE];
    }
    float w0 = __expf(lrelu(as_[s0] + add));
    float w1 = __expf(lrelu(as_[s1] + add));
    float w2 = __expf(lrelu(as_[s2] + add));
    float w3 = __expf(lrelu(as_[s3] + add));
    wsum += (w0 + w1) + (w2 + w3);
    #pragma unroll
    for (int c = 0; c < CPL; ++c)
      acc[c] += w0 * r0[c] + w1 * r1[c] + w2 * r2[c] + w3 * r3[c];
  }
  for (; j < o1; ++j){
    int s = csr_src[j];
    float w = __expf(lrelu(as_[s] + add));
    wsum += w;
    #pragma unroll
    for (int c = 0; c < CPL; ++c) acc[c] += w * h[(size_t)s * F + lane + c * WAVE];
  }
  float inv = 1.f / (wsum + 1e-16f);
  #pragma unroll
  for (int c = 0; c < CPL; ++c){
    float v = acc[c] * inv + bias[lane + c * WAVE];
    outp[(size_t)node * F + lane + c * WAVE] = fmaxf(v, 0.f);
  }
}

// ---------------- pooling (batch sorted): strip reduction ----------------
__global__ void k_pool(const float* __restrict__ h, const int* __restrict__ batch,
                       float* __restrict__ pool, int* __restrict__ cnt, int N, int strip){
  int f = threadIdx.x;  // 0..127
  int n0 = blockIdx.x * strip;
  if (n0 >= N) return;
  int n1 = min(n0 + strip, N);
  int g = batch[n0];
  float acc = 0.f;
  int c = 0;
  for (int n = n0; n < n1; ++n){
    int gn = batch[n];
    if (gn != g){
      atomicAdd(&pool[g * F2 + f], acc);
      if (f == 0) atomicAdd(&cnt[g], c);
      acc = 0.f; c = 0; g = gn;
    }
    acc += h[(size_t)n * F2 + f];
    c++;
  }
  atomicAdd(&pool[g * F2 + f], acc);
  if (f == 0) atomicAdd(&cnt[g], c);
}

// ---------------- final FC ----------------
__global__ void k_fc(const float* __restrict__ pool, const int* __restrict__ cnt,
                     const float* __restrict__ Wfc, const float* __restrict__ bfc,
                     float* __restrict__ out){
  int g = blockIdx.x, o = threadIdx.x;  // 64 x 64
  __shared__ float p[F2];
  float invc = 1.f / fmaxf((float)cnt[g], 1.f);
  for (int k = threadIdx.x; k < F2; k += 64) p[k] = pool[g * F2 + k] * invc;
  __syncthreads();
  float acc = bfc[o];
  for (int k = 0; k < F2; ++k) acc += p[k] * Wfc[k * 64 + o];
  out[g * 64 + o] = acc;
}

extern "C" void kernel_launch(void* const* d_in, const int* in_sizes, int n_in,
                              void* d_out, int out_size, void* d_ws, size_t ws_size,
                              hipStream_t stream){
  const float* x    = (const float*)d_in[0];
  const int*   edge = (const int*)d_in[1];
  const int*   batch= (const int*)d_in[2];
  const float* W1   = (const float*)d_in[3];
  const float* av_s1= (const float*)d_in[4];
  const float* av_d1= (const float*)d_in[5];
  const float* b1   = (const float*)d_in[6];
  const float* W2   = (const float*)d_in[7];
  const float* av_s2= (const float*)d_in[8];
  const float* av_d2= (const float*)d_in[9];
  const float* b2   = (const float*)d_in[10];
  const float* Wfc  = (const float*)d_in[11];
  const float* bfc  = (const float*)d_in[12];
  float* out = (float*)d_out;

  const int N  = in_sizes[2];
  const int E  = in_sizes[1] / 2;
  const int Et = E + N;
  const int NB = (N + 255) >> 8;       // coarse buckets (<= 256 for N <= 65536)
  const int* src = edge;
  const int* dst = edge + E;

  char* p = (char*)d_ws;
  auto alloc = [&](size_t bytes)->void*{
    void* r = (void*)p;
    p += (bytes + 255) & ~(size_t)255;
    return r;
  };
  float* h1   = (float*)alloc((size_t)N * F1 * 4);
  float* h1r  = (float*)alloc((size_t)N * F1 * 4);
  float* h2   = (float*)alloc((size_t)N * F2 * 4);
  float* h2r  = (float*)alloc((size_t)N * F2 * 4);
  float* as1  = (float*)alloc((size_t)N * 4);
  float* ad1  = (float*)alloc((size_t)N * 4);
  float* as2  = (float*)alloc((size_t)N * 4);
  float* ad2  = (float*)alloc((size_t)N * 4);
  float* pool = (float*)alloc((size_t)NG * F2 * 4);
  int* off    = (int*)alloc((size_t)(N + 1) * 4);
  int* csr_src= (int*)alloc((size_t)Et * 4);
  int* tmp    = (int*)alloc((size_t)Et * 4);
  int* cnt1   = (int*)alloc((size_t)256 * NBLK1 * 4);
  int* btot   = (int*)alloc((size_t)256 * 4);
  int* bbase  = (int*)alloc((size_t)257 * 4);
  int* cnt    = (int*)alloc((size_t)NG * 4);

  hipMemsetAsync(pool, 0, (size_t)NG * F2 * 4, stream);
  hipMemsetAsync(cnt, 0, (size_t)NG * 4, stream);

  // CSR build (no global atomics)
  int chunk = (Et + NBLK1 - 1) / NBLK1;
  k_hist<<<NBLK1, 256, 0, stream>>>(src, dst, E, N, NB, chunk, cnt1);
  k_colscan<<<NB, 256, 0, stream>>>(cnt1, btot);
  k_bucketscan<<<1, 256, 0, stream>>>(btot, NB, Et, bbase, off, N);
  k_scatter1<<<NBLK1, 256, 0, stream>>>(src, dst, E, N, NB, chunk, cnt1, bbase, tmp);
  k_sort2<<<NB, 256, 0, stream>>>(tmp, bbase, N, off, csr_src);

  // layer 1
  int gemm_waves = (N + 3) / 4;
  int gemm_blocks = (gemm_waves + 3) / 4;
  k_gemm<D_IN, F1><<<gemm_blocks, 256, 0, stream>>>(x, W1, av_s1, av_d1, h1, as1, ad1, N);
  int node_blocks = (N + 3) / 4;  // 4 waves per 256-thread block
  k_node<F1><<<node_blocks, 256, 0, stream>>>(off, csr_src, h1, as1, ad1, b1, h1r, N);

  // layer 2
  k_gemm<F1, F2><<<gemm_blocks, 256, 0, stream>>>(h1r, W2, av_s2, av_d2, h2, as2, ad2, N);
  k_node<F2><<<node_blocks, 256, 0, stream>>>(off, csr_src, h2, as2, ad2, b2, h2r, N);

  // pooling + FC
  int strip = 128;
  int pool_blocks = (N + strip - 1) / strip;
  k_pool<<<pool_blocks, F2, 0, stream>>>(h2r, batch, pool, cnt, N, strip);
  k_fc<<<NG, 64, 0, stream>>>(pool, cnt, Wfc, bfc, out);
}